// Round 1
// baseline (683.846 us; speedup 1.0000x reference)
//
#include <hip/hip_runtime.h>
#include <stdint.h>

#define B_ 32
#define S_ 2048
#define D_ 1024

typedef __attribute__((ext_vector_type(8))) short short8;
typedef __attribute__((ext_vector_type(4))) float f32x4;

__device__ __forceinline__ uint16_t f2bf(float f) {
  uint32_t u = __builtin_bit_cast(uint32_t, f);
  u += 0x7FFFu + ((u >> 16) & 1u);
  return (uint16_t)(u >> 16);
}

__device__ __forceinline__ void async_copy16(const void* g, void* l) {
  __builtin_amdgcn_global_load_lds(
      (const __attribute__((address_space(1))) uint32_t*)g,
      (__attribute__((address_space(3))) uint32_t*)l, 16, 0, 0);
}

// ---------------- column stats: sum and sumsq per (b,d) ----------------
__global__ void stats_kernel(const float* __restrict__ x,
                             float* __restrict__ sumB,
                             float* __restrict__ sumsqB) {
  int d  = blockIdx.x * 256 + threadIdx.x;  // gridDim.x = 4
  int s0 = blockIdx.y * 256;                // gridDim.y = 8
  int b  = blockIdx.z;                      // gridDim.z = 32
  const float* p = x + ((size_t)b * S_ + s0) * D_ + d;
  float s = 0.f, q = 0.f;
#pragma unroll 8
  for (int i = 0; i < 256; ++i) {
    float v = p[(size_t)i * D_];
    s += v;
    q += v * v;
  }
  atomicAdd(sumB + b * D_ + d, s);
  atomicAdd(sumsqB + b * D_ + d, q);
}

__global__ void finalize_kernel(const float* __restrict__ sumB,
                                const float* __restrict__ sumsqB,
                                float* __restrict__ meanB,
                                float* __restrict__ stdB) {
  int i = blockIdx.x * 256 + threadIdx.x;  // 32768 total
  float s = sumB[i], q = sumsqB[i];
  float m = s * (1.0f / (float)S_);
  float var = (q - s * m) * (1.0f / (float)(S_ - 1));
  meanB[i] = m;
  stdB[i] = sqrtf(fmaxf(var, 0.f));
}

// ---------------- transpose + bf16 cast into MFMA-ready images ----------------
// Image for (b, dtile, kslab): layout [kg=0..3][m=0..127][j=0..7] bf16 (8 KB),
// element = x[b][kslab*32 + kg*8 + j][dtile*128 + m]
__global__ void prepass_kernel(const float* __restrict__ x,
                               uint16_t* __restrict__ xt) {
  int dt = blockIdx.x;  // 0..7
  int ks = blockIdx.y;  // 0..63
  int b  = blockIdx.z;  // 0..31
  int tid = threadIdx.x;
  size_t imgBase = (((size_t)b * 8 + dt) * 64 + ks) * 4096;
  for (int it = tid; it < 512; it += 256) {
    int kg = it >> 7, m = it & 127;
    const float* src = x + ((size_t)b * S_ + (size_t)ks * 32 + kg * 8) * D_ + dt * 128 + m;
    uint32_t pk[4];
#pragma unroll
    for (int jj = 0; jj < 4; ++jj) {
      uint16_t lo = f2bf(src[(size_t)(2 * jj) * D_]);
      uint16_t hi = f2bf(src[(size_t)(2 * jj + 1) * D_]);
      pk[jj] = (uint32_t)lo | ((uint32_t)hi << 16);
    }
    *(uint4*)(xt + imgBase + (size_t)(kg * 128 + m) * 8) =
        make_uint4(pk[0], pk[1], pk[2], pk[3]);
  }
}

// ---------------- Gram (upper-triangle tiles) + threshold + colkill ----------------
__global__ __launch_bounds__(256) void gram_kernel(const uint16_t* __restrict__ xt,
                                                   const float* __restrict__ meanB,
                                                   const float* __restrict__ stdB,
                                                   int* __restrict__ colkill) {
  __shared__ uint8_t sm[16384];  // A image 8KB | B image 8KB
  int b = blockIdx.y;
  int p = blockIdx.x;  // 0..35 -> (i,j), i<=j
  int i = 0;
  while (p >= 8 - i) { p -= 8 - i; ++i; }
  int j = i + p;

  int tid = threadIdx.x;
  int lane = tid & 63, wave = tid >> 6;
  int wm = wave & 1, wn = wave >> 1;
  int quad = lane >> 4, r16 = lane & 15;

  f32x4 acc[4][4];
#pragma unroll
  for (int a = 0; a < 4; ++a)
#pragma unroll
    for (int c = 0; c < 4; ++c) acc[a][c] = (f32x4){0.f, 0.f, 0.f, 0.f};

  const char* gA = (const char*)(xt + ((size_t)b * 8 + i) * 64 * 4096);
  const char* gB = (const char*)(xt + ((size_t)b * 8 + j) * 64 * 4096);

  for (int ks = 0; ks < 64; ++ks) {
    __syncthreads();  // prior readers done before overwrite
    const char* srcA = gA + (size_t)ks * 8192;
    const char* srcB = gB + (size_t)ks * 8192;
    for (int c = wave; c < 8; c += 4) {
      async_copy16(srcA + c * 1024 + lane * 16, (void*)(sm + c * 1024));
      async_copy16(srcB + c * 1024 + lane * 16, (void*)(sm + 8192 + c * 1024));
    }
    __syncthreads();  // drains vmcnt incl. global_load_lds

    short8 af[4], bfr[4];
#pragma unroll
    for (int t = 0; t < 4; ++t) {
      af[t]  = *(const short8*)(sm + ((size_t)(quad * 128 + wm * 64 + t * 16 + r16)) * 16);
      bfr[t] = *(const short8*)(sm + 8192 + ((size_t)(quad * 128 + wn * 64 + t * 16 + r16)) * 16);
    }
#pragma unroll
    for (int mt = 0; mt < 4; ++mt)
#pragma unroll
      for (int nt = 0; nt < 4; ++nt)
        acc[mt][nt] = __builtin_amdgcn_mfma_f32_16x16x32_bf16(af[mt], bfr[nt], acc[mt][nt], 0, 0, 0);
  }

  // epilogue: cov from raw Gram, threshold vs 0.5*std_d*std_e, kill both cols
  const float* mb = meanB + b * D_;
  const float* sb = stdB + b * D_;
  int dBase = i * 128 + wm * 64;
  int eBase = j * 128 + wn * 64;
#pragma unroll
  for (int nt = 0; nt < 4; ++nt) {
    int e = eBase + nt * 16 + r16;
    float me = mb[e], se = sb[e];
#pragma unroll
    for (int mt = 0; mt < 4; ++mt) {
#pragma unroll
      for (int r = 0; r < 4; ++r) {
        int d = dBase + mt * 16 + quad * 4 + r;
        float cov = (acc[mt][nt][r] - (float)S_ * mb[d] * me) * (1.0f / (float)(S_ - 1));
        if (d != e && fabsf(cov) > 0.5f * sb[d] * se) {
          atomicOr(colkill + b * D_ + e, 1);
          atomicOr(colkill + b * D_ + d, 1);
        }
      }
    }
  }
}

// ---------------- apply mask ----------------
__global__ void apply_kernel(const float* __restrict__ x,
                             const int* __restrict__ colkill,
                             float* __restrict__ out) {
  size_t idx = (size_t)blockIdx.x * 256 + threadIdx.x;  // float4 index
  const float4 v = ((const float4*)x)[idx];
  size_t e0 = idx * 4;
  int d = (int)(e0 & (D_ - 1));
  int b = (int)(e0 >> 21);  // S_*D_ = 2^21
  const int4 k = *(const int4*)(colkill + b * D_ + d);
  float4 o;
  o.x = k.x ? 0.f : v.x;
  o.y = k.y ? 0.f : v.y;
  o.z = k.z ? 0.f : v.z;
  o.w = k.w ? 0.f : v.w;
  ((float4*)out)[idx] = o;
}

extern "C" void kernel_launch(void* const* d_in, const int* in_sizes, int n_in,
                              void* d_out, int out_size, void* d_ws, size_t ws_size,
                              hipStream_t stream) {
  const float* x = (const float*)d_in[0];
  float* out = (float*)d_out;

  // bf16 images live in d_out (134 MB < 268 MB); apply_kernel fully overwrites later.
  uint16_t* xt = (uint16_t*)d_out;

  // small stats buffers in ws: 5 * 128 KB
  float* sumB   = (float*)d_ws;
  float* sumsqB = sumB + 32768;
  float* meanB  = sumB + 65536;
  float* stdB   = sumB + 98304;
  int*   colkill = (int*)(sumB + 131072);

  hipMemsetAsync(sumB, 0, 5 * 32768 * sizeof(float), stream);
  stats_kernel<<<dim3(4, 8, 32), 256, 0, stream>>>(x, sumB, sumsqB);
  finalize_kernel<<<128, 256, 0, stream>>>(sumB, sumsqB, meanB, stdB);
  prepass_kernel<<<dim3(8, 64, 32), 256, 0, stream>>>(x, xt);
  gram_kernel<<<dim3(36, 32), 256, 0, stream>>>(xt, meanB, stdB, colkill);
  apply_kernel<<<65536, 256, 0, stream>>>(x, colkill, out);
}

// Round 2
// 571.993 us; speedup vs baseline: 1.1955x; 1.1955x over previous
//
#include <hip/hip_runtime.h>
#include <stdint.h>

#define B_ 32
#define S_ 2048
#define D_ 1024

typedef __attribute__((ext_vector_type(16))) float f32x16;

__device__ __forceinline__ void async_copy16(const void* g, void* l) {
  __builtin_amdgcn_global_load_lds(
      (const __attribute__((address_space(1))) uint32_t*)g,
      (__attribute__((address_space(3))) uint32_t*)l, 16, 0, 0);
}

// image row layout: per (b,dt) image = 16 slabs x (128 m-rows x 128 bytes).
// Row m, slab-local k in [0,128): 8 chunks of 16B. Chunk ch=(g<<1)|bh holds
// fp8 of local k = g*32+bh*8+{0..7} (bytes 0-7) and g*32+16+bh*8+{0..7}
// (bytes 8-15), stored at position (ch ^ (m&7))*16  [XOR swizzle: makes the
// gram's stride-128B b128 frag reads conflict-free across 32 lanes].
__device__ __forceinline__ int row_off(int m, int ch) {
  return m * 128 + ((ch ^ (m & 7)) << 4);
}

// ---------------- prepass: transpose + fp8 cast + fused column stats ----------------
__global__ __launch_bounds__(256) void prepass_kernel(const float* __restrict__ x,
                                                      uint8_t* __restrict__ xt,
                                                      float2* __restrict__ part) {
  __shared__ float s_s[256 * 4];
  __shared__ float s_q[256 * 4];
  int dt = blockIdx.x;    // 0..7
  int slab = blockIdx.y;  // 0..15
  int b = blockIdx.z;     // 0..31
  int t = threadIdx.x;
  int q = t & 31;   // m-quad: columns 4q..4q+3
  int e = t >> 5;   // eighth: g = e>>1, bh = e&1
  int g = e >> 1, bh = e & 1;

  const float* xb = x + ((size_t)b * S_ + (size_t)slab * 128 + g * 32 + bh * 8) * D_ +
                    dt * 128 + q * 4;
  float4 r[16];
#pragma unroll
  for (int j = 0; j < 8; ++j) r[j] = *(const float4*)(xb + (size_t)j * D_);
#pragma unroll
  for (int j = 0; j < 8; ++j) r[8 + j] = *(const float4*)(xb + (size_t)(16 + j) * D_);

  uint8_t* img = xt + (((size_t)b * 8 + dt) * 16 + slab) * 16384;
#pragma unroll
  for (int c = 0; c < 4; ++c) {
    float v[16];
#pragma unroll
    for (int j = 0; j < 16; ++j) v[j] = ((const float*)&r[j])[c];
    float ps = 0.f, pq = 0.f;
#pragma unroll
    for (int j = 0; j < 16; ++j) { ps += v[j]; pq += v[j] * v[j]; }
    s_s[t * 4 + c] = ps;
    s_q[t * 4 + c] = pq;
    uint32_t w0 = 0, w1 = 0, w2 = 0, w3 = 0;
    w0 = __builtin_amdgcn_cvt_pk_fp8_f32(v[0], v[1], w0, false);
    w0 = __builtin_amdgcn_cvt_pk_fp8_f32(v[2], v[3], w0, true);
    w1 = __builtin_amdgcn_cvt_pk_fp8_f32(v[4], v[5], w1, false);
    w1 = __builtin_amdgcn_cvt_pk_fp8_f32(v[6], v[7], w1, true);
    w2 = __builtin_amdgcn_cvt_pk_fp8_f32(v[8], v[9], w2, false);
    w2 = __builtin_amdgcn_cvt_pk_fp8_f32(v[10], v[11], w2, true);
    w3 = __builtin_amdgcn_cvt_pk_fp8_f32(v[12], v[13], w3, false);
    w3 = __builtin_amdgcn_cvt_pk_fp8_f32(v[14], v[15], w3, true);
    int m = 4 * q + c;
    *(uint4*)(img + row_off(m, (g << 1) | bh)) = make_uint4(w0, w1, w2, w3);
  }
  __syncthreads();
  if (t < 128) {
    int m = t, qq = m >> 2, cc = m & 3;
    float ss = 0.f, sq = 0.f;
#pragma unroll
    for (int ee = 0; ee < 8; ++ee) {
      ss += s_s[(qq + 32 * ee) * 4 + cc];
      sq += s_q[(qq + 32 * ee) * 4 + cc];
    }
    part[(size_t)slab * 32768 + b * 1024 + dt * 128 + m] = make_float2(ss, sq);
  }
}

__global__ void finalize_kernel(const float2* __restrict__ part,
                                float* __restrict__ meanB,
                                float* __restrict__ stdB) {
  int i = blockIdx.x * 256 + threadIdx.x;  // 32768 = (b,d)
  float s = 0.f, qv = 0.f;
#pragma unroll
  for (int sl = 0; sl < 16; ++sl) {
    float2 p = part[(size_t)sl * 32768 + i];
    s += p.x;
    qv += p.y;
  }
  float m = s * (1.0f / (float)S_);
  float var = (qv - s * m) * (1.0f / (float)(S_ - 1));
  meanB[i] = m;
  stdB[i] = sqrtf(fmaxf(var, 0.f));
}

// ---------------- Gram (upper-triangle tiles, fp8 MFMA) + threshold + colkill ----------------
__global__ __launch_bounds__(256) void gram_kernel(const uint8_t* __restrict__ xt,
                                                   const float* __restrict__ meanB,
                                                   const float* __restrict__ stdB,
                                                   int* __restrict__ colkill) {
  __shared__ uint8_t smA[16384];
  __shared__ uint8_t smB[16384];
  int b = blockIdx.y;
  int p = blockIdx.x;  // 0..35 -> (i,j), i<=j
  int i = 0;
  while (p >= 8 - i) { p -= 8 - i; ++i; }
  int j = i + p;

  int tid = threadIdx.x;
  int lane = tid & 63, wave = tid >> 6;
  int wm = wave & 1, wn = wave >> 1;
  int l31 = lane & 31, half = lane >> 5;

  f32x16 acc[2][2];
#pragma unroll
  for (int a = 0; a < 2; ++a)
#pragma unroll
    for (int c = 0; c < 2; ++c)
#pragma unroll
      for (int r = 0; r < 16; ++r) acc[a][c][r] = 0.f;

  const uint8_t* gA = xt + ((size_t)b * 8 + i) * 262144;
  const uint8_t* gB = xt + ((size_t)b * 8 + j) * 262144;
  bool diag = (i == j);

  for (int sl = 0; sl < 16; ++sl) {
    __syncthreads();
    const uint8_t* srcA = gA + (size_t)sl * 16384;
    for (int c = wave; c < 16; c += 4)
      async_copy16(srcA + c * 1024 + lane * 16, (void*)(smA + c * 1024));
    if (!diag) {
      const uint8_t* srcB = gB + (size_t)sl * 16384;
      for (int c = wave; c < 16; c += 4)
        async_copy16(srcB + c * 1024 + lane * 16, (void*)(smB + c * 1024));
    }
    __syncthreads();

    const uint8_t* bA = smA;
    const uint8_t* bB = diag ? smA : smB;
#pragma unroll
    for (int g = 0; g < 4; ++g) {
      ulonglong2 a0 = *(const ulonglong2*)(bA + row_off(wm * 64 + l31, (g << 1) | half));
      ulonglong2 a1 = *(const ulonglong2*)(bA + row_off(wm * 64 + 32 + l31, (g << 1) | half));
      ulonglong2 b0 = *(const ulonglong2*)(bB + row_off(wn * 64 + l31, (g << 1) | half));
      ulonglong2 b1 = *(const ulonglong2*)(bB + row_off(wn * 64 + 32 + l31, (g << 1) | half));
      acc[0][0] = __builtin_amdgcn_mfma_f32_32x32x16_fp8_fp8((long)a0.x, (long)b0.x, acc[0][0], 0, 0, 0);
      acc[0][1] = __builtin_amdgcn_mfma_f32_32x32x16_fp8_fp8((long)a0.x, (long)b1.x, acc[0][1], 0, 0, 0);
      acc[1][0] = __builtin_amdgcn_mfma_f32_32x32x16_fp8_fp8((long)a1.x, (long)b0.x, acc[1][0], 0, 0, 0);
      acc[1][1] = __builtin_amdgcn_mfma_f32_32x32x16_fp8_fp8((long)a1.x, (long)b1.x, acc[1][1], 0, 0, 0);
      acc[0][0] = __builtin_amdgcn_mfma_f32_32x32x16_fp8_fp8((long)a0.y, (long)b0.y, acc[0][0], 0, 0, 0);
      acc[0][1] = __builtin_amdgcn_mfma_f32_32x32x16_fp8_fp8((long)a0.y, (long)b1.y, acc[0][1], 0, 0, 0);
      acc[1][0] = __builtin_amdgcn_mfma_f32_32x32x16_fp8_fp8((long)a1.y, (long)b0.y, acc[1][0], 0, 0, 0);
      acc[1][1] = __builtin_amdgcn_mfma_f32_32x32x16_fp8_fp8((long)a1.y, (long)b1.y, acc[1][1], 0, 0, 0);
    }
  }

  // epilogue: cov from raw Gram, threshold vs 0.5*std_d*std_e, kill both cols
  const float* mb = meanB + b * D_;
  const float* sb = stdB + b * D_;
#pragma unroll
  for (int t = 0; t < 2; ++t) {
#pragma unroll
    for (int u = 0; u < 2; ++u) {
      int e = j * 128 + wn * 64 + u * 32 + l31;
      float me = mb[e], se05 = 0.5f * sb[e];
#pragma unroll
      for (int r = 0; r < 16; ++r) {
        int row = half * 4 + (r & 3) + 8 * (r >> 2);
        int d = i * 128 + wm * 64 + t * 32 + row;
        float cov = (acc[t][u][r] - (float)S_ * mb[d] * me) * (1.0f / (float)(S_ - 1));
        if (d != e && fabsf(cov) > se05 * sb[d]) {
          atomicOr(colkill + b * D_ + e, 1);
          atomicOr(colkill + b * D_ + d, 1);
        }
      }
    }
  }
}

// ---------------- apply mask ----------------
__global__ void apply_kernel(const float* __restrict__ x,
                             const int* __restrict__ colkill,
                             float* __restrict__ out) {
  size_t idx = (size_t)blockIdx.x * 256 + threadIdx.x;  // float4 index
  const float4 v = ((const float4*)x)[idx];
  size_t e0 = idx * 4;
  int d = (int)(e0 & (D_ - 1));
  int b = (int)(e0 >> 21);  // S_*D_ = 2^21
  const int4 k = *(const int4*)(colkill + b * D_ + d);
  float4 o;
  o.x = k.x ? 0.f : v.x;
  o.y = k.y ? 0.f : v.y;
  o.z = k.z ? 0.f : v.z;
  o.w = k.w ? 0.f : v.w;
  ((float4*)out)[idx] = o;
}

extern "C" void kernel_launch(void* const* d_in, const int* in_sizes, int n_in,
                              void* d_out, int out_size, void* d_ws, size_t ws_size,
                              hipStream_t stream) {
  const float* x = (const float*)d_in[0];
  float* out = (float*)d_out;

  // fp8 images live in d_out (64 MiB < 268 MB); apply_kernel fully overwrites later.
  uint8_t* xt = (uint8_t*)d_out;

  // ws: part [16][32768] float2 = 4 MiB, then meanB/stdB/colkill (128 KB each)
  float2* part = (float2*)d_ws;
  float* meanB = (float*)((uint8_t*)d_ws + (16 * 32768) * sizeof(float2));
  float* stdB = meanB + 32768;
  int* colkill = (int*)(stdB + 32768);

  hipMemsetAsync(colkill, 0, 32768 * sizeof(int), stream);
  prepass_kernel<<<dim3(8, 16, 32), 256, 0, stream>>>(x, xt, part);
  finalize_kernel<<<128, 256, 0, stream>>>(part, meanB, stdB);
  gram_kernel<<<dim3(36, 32), 256, 0, stream>>>(xt, meanB, stdB, colkill);
  apply_kernel<<<65536, 256, 0, stream>>>(x, colkill, out);
}